// Round 8
// baseline (171.617 us; speedup 1.0000x reference)
//
#include <hip/hip_runtime.h>
#include <hip/hip_bf16.h>
#include <math.h>

#define D_MODEL 1024
#define N_HEADS 16
#define D_K     64
#define BATCH   2
#define SEQ     2048
#define M_TOTAL (BATCH * SEQ)   // 4096

typedef __attribute__((ext_vector_type(8))) short short8;    // 8 bf16 = 4 VGPR
typedef __attribute__((ext_vector_type(2))) float f32x2;
typedef __attribute__((ext_vector_type(4))) float f32x4;
typedef __attribute__((ext_vector_type(16))) float f32x16;

__device__ __forceinline__ ushort f2bf(float f) {
    __hip_bfloat16 h = __float2bfloat16(f);
    union { __hip_bfloat16 h; ushort u; } c; c.h = h; return c.u;
}

// packed bf16 convert (RNE on gfx950): lo = cvt(a), hi = cvt(b)
__device__ __forceinline__ uint cvtpk(float a, float b) {
    uint r;
    asm("v_cvt_pk_bf16_f32 %0, %1, %2" : "=v"(r) : "v"(a), "v"(b));
    return r;
}

// packed f32 ops (VOP3P, CDNA): lane-wise on 2-wide f32 register pairs
__device__ __forceinline__ f32x2 pk_mul(f32x2 a, f32x2 b) {
    f32x2 d;
    asm("v_pk_mul_f32 %0, %1, %2" : "=v"(d) : "v"(a), "v"(b));
    return d;
}
__device__ __forceinline__ f32x2 pk_add(f32x2 a, f32x2 b) {
    f32x2 d;
    asm("v_pk_add_f32 %0, %1, %2" : "=v"(d) : "v"(a), "v"(b));
    return d;
}
__device__ __forceinline__ float max3f(float a, float b, float c) {
    float d;
    asm("v_max3_f32 %0, %1, %2, %3" : "=v"(d) : "v"(a), "v"(b), "v"(c));
    return d;
}

__device__ __forceinline__ void gload_lds16(const void* g, void* l) {
    __builtin_amdgcn_global_load_lds(
        (const __attribute__((address_space(1))) void*)g,
        (__attribute__((address_space(3))) void*)l, 16, 0, 0);
}

// v_permlane32_swap_b32 vdst, vsrc — exchange diagonal probed at runtime.
__device__ __forceinline__ void plswap(uint& a, uint& b) {
    asm volatile("v_permlane32_swap_b32 %0, %1" : "+v"(a), "+v"(b));
}

// ---------------------------------------------------------------------------
// Fused f32 -> bf16 cast for all 5 tensors in one launch.
// ---------------------------------------------------------------------------
__global__ __launch_bounds__(256) void cast_all(const float* __restrict__ x,
                                                const float* __restrict__ Wq,
                                                const float* __restrict__ Wk,
                                                const float* __restrict__ Wv,
                                                const float* __restrict__ Wo,
                                                ushort* __restrict__ xb,
                                                ushort* __restrict__ wqkv,
                                                ushort* __restrict__ wob)
{
    const int bi = blockIdx.x;
    const float* src; ushort* dst; int blk;
    const int NW = D_MODEL * D_MODEL;  // 1M
    if (bi < 4096)      { src = x;  dst = xb;            blk = bi; }
    else if (bi < 5120) { src = Wq; dst = wqkv;          blk = bi - 4096; }
    else if (bi < 6144) { src = Wk; dst = wqkv + NW;     blk = bi - 5120; }
    else if (bi < 7168) { src = Wv; dst = wqkv + 2 * NW; blk = bi - 6144; }
    else                { src = Wo; dst = wob;           blk = bi - 7168; }
    const int i = blk * 1024 + threadIdx.x * 4;
    float4 v = *(const float4*)&src[i];
    ushort4 o;
    o.x = f2bf(v.x); o.y = f2bf(v.y); o.z = f2bf(v.z); o.w = f2bf(v.w);
    *(ushort4*)&dst[i] = o;
}

// ---------------------------------------------------------------------------
// bf16 GEMM: C = A(M,K) * B(N,K)^T, fp32 accum via mfma_f32_16x16x32_bf16.
// 128x128 tile, BK=32, 256 thr (4 waves), global_load_lds w=16,
// double-buffered LDS with vmcnt-before-barrier prefetch.
// EPI 0: C fp32 row-major [M][N].
// EPI 1: QKV scatter: q,k bf16 [B,H,S,Dk] (q scaled by 0.125*log2e for the
//        exp2-domain softmax); v bf16 [B,H,Dk,S].
// ---------------------------------------------------------------------------
template <int EPI>
__global__ __launch_bounds__(256) void gemm_bf16(const ushort* __restrict__ A,
                                                 const ushort* __restrict__ B,
                                                 void* __restrict__ C0,
                                                 void* __restrict__ C1,
                                                 void* __restrict__ C2,
                                                 int M, int N, int K)
{
    __shared__ ushort As[2][4 * 128 * 8];
    __shared__ ushort Bs[2][4 * 128 * 8];

    const int tid = threadIdx.x;
    const int lane = tid & 63;
    const int w = tid >> 6;
    const int li = lane & 15;
    const int kg = lane >> 4;
    const int m0 = blockIdx.y * 128;
    const int n0 = blockIdx.x * 128;
    const int wr = (w >> 1) * 64;
    const int wc = (w & 1) * 64;

    f32x4 acc[4][4] = {};

    const int s1 = tid, s2 = tid + 256;
    const ushort* ga1 = &A[(size_t)(m0 + (s1 & 127)) * K + (s1 >> 7) * 8];
    const ushort* ga2 = &A[(size_t)(m0 + (s2 & 127)) * K + (s2 >> 7) * 8];
    const ushort* gb1 = &B[(size_t)(n0 + (s1 & 127)) * K + (s1 >> 7) * 8];
    const ushort* gb2 = &B[(size_t)(n0 + (s2 & 127)) * K + (s2 >> 7) * 8];

    const int NT = K / 32;
    gload_lds16(ga1, &As[0][s1 * 8]);
    gload_lds16(ga2, &As[0][s2 * 8]);
    gload_lds16(gb1, &Bs[0][s1 * 8]);
    gload_lds16(gb2, &Bs[0][s2 * 8]);

    for (int t = 0; t < NT; ++t) {
        const int cur = t & 1;
        asm volatile("s_waitcnt vmcnt(0)" ::: "memory");
        __syncthreads();
        if (t + 1 < NT) {
            const int kb = (t + 1) * 32;
            const int nxt = cur ^ 1;
            gload_lds16(ga1 + kb, &As[nxt][s1 * 8]);
            gload_lds16(ga2 + kb, &As[nxt][s2 * 8]);
            gload_lds16(gb1 + kb, &Bs[nxt][s1 * 8]);
            gload_lds16(gb2 + kb, &Bs[nxt][s2 * 8]);
        }
        short8 af[4], bf_[4];
#pragma unroll
        for (int m = 0; m < 4; ++m)
            af[m] = *(const short8*)&As[cur][(kg * 128 + wr + m * 16 + li) * 8];
#pragma unroll
        for (int n = 0; n < 4; ++n)
            bf_[n] = *(const short8*)&Bs[cur][(kg * 128 + wc + n * 16 + li) * 8];
#pragma unroll
        for (int m = 0; m < 4; ++m)
#pragma unroll
            for (int n = 0; n < 4; ++n)
                acc[m][n] = __builtin_amdgcn_mfma_f32_16x16x32_bf16(
                    af[m], bf_[n], acc[m][n], 0, 0, 0);
    }

    if (EPI == 1) {
        ushort* q = (ushort*)C0; ushort* k = (ushort*)C1; ushort* v = (ushort*)C2;
        const float QSCALE = 0.125f * 1.44269504088896f;   // fold log2(e)
#pragma unroll
        for (int m = 0; m < 4; ++m) {
            const int Rb = m0 + wr + m * 16 + kg * 4;
#pragma unroll
            for (int n = 0; n < 4; ++n) {
                const int Ncol = n0 + wc + n * 16 + li;
                const int proj = Ncol >> 10;
                const int rem = Ncol & 1023;
                const int h = rem >> 6, dk = rem & 63;
#pragma unroll
                for (int r = 0; r < 4; ++r) {
                    const int R = Rb + r;
                    const int b = R >> 11, s = R & 2047;
                    const int bh = b * N_HEADS + h;
                    if (proj == 0)
                        q[((size_t)bh * SEQ + s) * D_K + dk] = f2bf(acc[m][n][r] * QSCALE);
                    else if (proj == 1)
                        k[((size_t)bh * SEQ + s) * D_K + dk] = f2bf(acc[m][n][r]);
                    else  // V stored transposed: [B,H,Dk,S]
                        v[((size_t)bh * D_K + dk) * SEQ + s] = f2bf(acc[m][n][r]);
                }
            }
        }
    } else {
        float* C = (float*)C0;
#pragma unroll
        for (int m = 0; m < 4; ++m) {
            const int Rb = m0 + wr + m * 16 + kg * 4;
#pragma unroll
            for (int n = 0; n < 4; ++n) {
                const int Ncol = n0 + wc + n * 16 + li;
#pragma unroll
                for (int r = 0; r < 4; ++r)
                    C[(size_t)(Rb + r) * N + Ncol] = acc[m][n][r];
            }
        }
    }
}

// ---------------------------------------------------------------------------
// MFMA flash attention, 32x32 swapped form, in-block KV-split (8 waves).
// R8: VALU-trimmed softmax — sub-free exp (p = 2^s * 2^-m with c maintained
// at rescale events), v_pk_mul/add_f32 for the p/ts path, v_max3_f32 tree.
// ---------------------------------------------------------------------------
__global__ __launch_bounds__(512, 4) void attn_mfma(const ushort* __restrict__ Q,
                                                    const ushort* __restrict__ K,
                                                    const ushort* __restrict__ Vt,
                                                    ushort* __restrict__ AO)
{
    __shared__ ushort pool[2][2][2][64 * 64];   // [stream kvh][K/V][buf][8KB]

    const int tid = threadIdx.x, lane = tid & 63, w = tid >> 6;
    const int wq = w & 3, kvh = w >> 2;
    const int r31 = lane & 31, hi = lane >> 5;
    const int b = blockIdx.z, h = blockIdx.y, q0 = blockIdx.x * 128;
    const int bh = b * N_HEADS + h;
    const size_t base = (size_t)bh * SEQ * D_K;    // Q, K
    const size_t vbase = (size_t)bh * D_K * SEQ;   // Vt

    // --- probe the permlane32_swap diagonal (wave-uniform) ---
    uint pa = (uint)lane, pbv = 1000u + (uint)lane;
    plswap(pa, pbv);
    const bool swap_lo = (__builtin_amdgcn_readfirstlane(pa) > 500u);

    // Q B-frags: col=q=r31, k(dk) = ks*16 + hi*8 + j
    const size_t qrow = base + (size_t)(q0 + wq * 32 + r31) * D_K;
    short8 qb[4];
#pragma unroll
    for (int ks = 0; ks < 4; ++ks)
        qb[ks] = *(const short8*)&Q[qrow + ks * 16 + hi * 8];

    float m_ = -INFINITY, l_ = 0.f;
    f32x2 cpair = {0.f, 0.f};       // {2^-m, 2^-m}, valid after first rescale
    f32x16 o0 = {}, o1 = {};        // O^T: col=q=r31

    const int srow_l = lane >> 3;   // 0..7
    const int sblk = lane & 7;
    const ushort* Kt0 = &K[base];
    const ushort* Vt0 = &Vt[vbase];
    const int tile0 = kvh * 16;     // this group's first KV tile

    // hoisted lane-constant LDS read offsets (elements)
    const int xr = r31 & 7;
    int off[2][4];
#pragma unroll
    for (int hf = 0; hf < 2; ++hf)
#pragma unroll
        for (int ks = 0; ks < 4; ++ks)
            off[hf][ks] = hf * 2048 + r31 * 64 + (((2 * ks + hi) ^ xr) * 8);

    const ushort* Kst = &pool[kvh][0][0][0];
    const ushort* Vst = &pool[kvh][1][0][0];

#define STAGE(kt_, buf_)                                                       \
    {                                                                          \
        _Pragma("unroll")                                                      \
        for (int p = 0; p < 2; ++p) {                                          \
            const int row = wq * 16 + p * 8 + srow_l;                          \
            const int db = sblk ^ (row & 7);                                   \
            gload_lds16(Kt0 + ((size_t)((tile0 + (kt_)) * 64 + row)) * D_K + db * 8, \
                        &pool[kvh][0][buf_][(wq * 16 + p * 8) * 64]);          \
            gload_lds16(Vt0 + (size_t)row * SEQ + (tile0 + (kt_)) * 64 + db * 8,     \
                        &pool[kvh][1][buf_][(wq * 16 + p * 8) * 64]);          \
        }                                                                      \
    }

    STAGE(0, 0);

    const int NT = SEQ / 64 / 2;    // 16 tiles per group
    for (int kt = 0; kt < NT; ++kt) {
        const int cur = kt & 1;
        asm volatile("s_waitcnt vmcnt(0)" ::: "memory");
        __syncthreads();
        if (kt + 1 < NT) STAGE(kt + 1, cur ^ 1);
        const int cb = cur * 4096;

        // S^T = mfma32(K, Q)
        f32x16 s0 = {}, s1 = {};
        __builtin_amdgcn_s_setprio(1);
#pragma unroll
        for (int ks = 0; ks < 4; ++ks) {
            short8 kb = *(const short8*)(Kst + cb + off[0][ks]);
            s0 = __builtin_amdgcn_mfma_f32_32x32x16_bf16(kb, qb[ks], s0, 0, 0, 0);
        }
#pragma unroll
        for (int ks = 0; ks < 4; ++ks) {
            short8 kb = *(const short8*)(Kst + cb + off[1][ks]);
            s1 = __builtin_amdgcn_mfma_f32_32x32x16_bf16(kb, qb[ks], s1, 0, 0, 0);
        }
        __builtin_amdgcn_s_setprio(0);

        // row max via max3 tree: 32 values -> 17 ops, + 1 shfl
        float t0 = max3f(s0[0], s0[1], s0[2]);
        float t1 = max3f(s0[3], s0[4], s0[5]);
        float t2 = max3f(s0[6], s0[7], s0[8]);
        float t3 = max3f(s0[9], s0[10], s0[11]);
        float t4 = max3f(s0[12], s0[13], s0[14]);
        float t5 = max3f(s0[15], s1[0], s1[1]);
        float t6 = max3f(s1[2], s1[3], s1[4]);
        float t7 = max3f(s1[5], s1[6], s1[7]);
        float t8 = max3f(s1[8], s1[9], s1[10]);
        float t9 = max3f(s1[11], s1[12], s1[13]);
        float ta = fmaxf(s1[14], s1[15]);
        t0 = max3f(t0, t1, t2);
        t3 = max3f(t3, t4, t5);
        t6 = max3f(t6, t7, t8);
        t9 = max3f(t9, ta, t0);
        float mx = max3f(t3, t6, t9);
        mx = fmaxf(mx, __shfl_xor(mx, 32, 64));

        // defer-max: rescale only when the running max grows by > 8 (log2)
        if (__any(mx > m_ + 8.0f)) {
            const float mn = fmaxf(m_, mx);
            const float sc = exp2f(m_ - mn);
            l_ *= sc;
#pragma unroll
            for (int e = 0; e < 16; ++e) { o0[e] *= sc; o1[e] *= sc; }
            m_ = mn;
            const float c = exp2f(-m_);
            cpair.x = c; cpair.y = c;
        }

        // p = 2^s * c (sub-free), packed mul/add; pairs feed cvt_pk directly
        f32x2 ts0 = {0.f, 0.f}, ts1 = {0.f, 0.f};
        uint u[8][2];
#pragma unroll
        for (int rq = 0; rq < 4; ++rq) {
            f32x2 ea = {exp2f(s0[4 * rq + 0]), exp2f(s0[4 * rq + 1])};
            f32x2 eb = {exp2f(s0[4 * rq + 2]), exp2f(s0[4 * rq + 3])};
            f32x2 pa_ = pk_mul(ea, cpair);
            f32x2 pb_ = pk_mul(eb, cpair);
            ts0 = pk_add(ts0, pa_);
            ts1 = pk_add(ts1, pb_);
            u[rq][0] = cvtpk(pa_.x, pa_.y);
            u[rq][1] = cvtpk(pb_.x, pb_.y);
        }
#pragma unroll
        for (int rq = 0; rq < 4; ++rq) {
            f32x2 ea = {exp2f(s1[4 * rq + 0]), exp2f(s1[4 * rq + 1])};
            f32x2 eb = {exp2f(s1[4 * rq + 2]), exp2f(s1[4 * rq + 3])};
            f32x2 pa_ = pk_mul(ea, cpair);
            f32x2 pb_ = pk_mul(eb, cpair);
            ts0 = pk_add(ts0, pa_);
            ts1 = pk_add(ts1, pb_);
            u[4 + rq][0] = cvtpk(pa_.x, pa_.y);
            u[4 + rq][1] = cvtpk(pb_.x, pb_.y);
        }
        f32x2 tsc = pk_add(ts0, ts1);
        float ts = tsc.x + tsc.y;
        ts += __shfl_xor(ts, 32, 64);
        l_ += ts;

        // per k-slice: B-frag = keys octet 2ks (x) + octet 2ks+1 (y), swapped
        short8 pb[4];
#pragma unroll
        for (int ks = 0; ks < 4; ++ks) {
            uint x0 = u[2 * ks][0], x1 = u[2 * ks][1];
            uint y0 = u[2 * ks + 1][0], y1 = u[2 * ks + 1][1];
            if (swap_lo) { plswap(y0, x0); plswap(y1, x1); }
            else         { plswap(x0, y0); plswap(x1, y1); }
            union { uint u4[4]; short8 s; } pu;
            pu.u4[0] = x0; pu.u4[1] = x1; pu.u4[2] = y0; pu.u4[3] = y1;
            pb[ks] = pu.s;
        }

        // O^T += mfma32(Vt, P^T)
        __builtin_amdgcn_s_setprio(1);
#pragma unroll
        for (int ks = 0; ks < 4; ++ks) {
            short8 vb = *(const short8*)(Vst + cb + off[0][ks]);
            o0 = __builtin_amdgcn_mfma_f32_32x32x16_bf16(vb, pb[ks], o0, 0, 0, 0);
        }
#pragma unroll
        for (int ks = 0; ks < 4; ++ks) {
            short8 vb = *(const short8*)(Vst + cb + off[1][ks]);
            o1 = __builtin_amdgcn_mfma_f32_32x32x16_bf16(vb, pb[ks], o1, 0, 0, 0);
        }
        __builtin_amdgcn_s_setprio(0);
    }
#undef STAGE

    // ---- merge the two KV halves through LDS (alias the staging pool) ----
    __syncthreads();
    float* cs = (float*)&pool[0][0][0][0];     // 4 waves * 64 lanes * 32 f = 32KB
    float* ml = cs + 4 * 64 * 32;              // + 512 floats
    const int cidx = (wq * 64 + lane) * 32;
    if (kvh == 1) {
#pragma unroll
        for (int rq = 0; rq < 4; ++rq) {
            f32x4 a, c;
#pragma unroll
            for (int e = 0; e < 4; ++e) { a[e] = o0[4 * rq + e]; c[e] = o1[4 * rq + e]; }
            *(f32x4*)&cs[cidx + 4 * rq] = a;
            *(f32x4*)&cs[cidx + 16 + 4 * rq] = c;
        }
        ml[(wq * 64 + lane) * 2]     = m_;
        ml[(wq * 64 + lane) * 2 + 1] = l_;
    }
    __syncthreads();
    if (kvh == 0) {
        const float m2 = ml[(wq * 64 + lane) * 2];
        const float l2 = ml[(wq * 64 + lane) * 2 + 1];
        const float mM = fmaxf(m_, m2);
        const float sc1 = exp2f(m_ - mM), sc2 = exp2f(m2 - mM);
        const float linv = 1.f / (l_ * sc1 + l2 * sc2);
        ushort* Ao = &AO[((size_t)b * SEQ + q0 + wq * 32 + r31) * D_MODEL + h * 64];
#pragma unroll
        for (int rq = 0; rq < 4; ++rq) {
            f32x4 a = *(const f32x4*)&cs[cidx + 4 * rq];
            f32x4 c = *(const f32x4*)&cs[cidx + 16 + 4 * rq];
            uint2 v0, v1;
            v0.x = cvtpk((o0[4 * rq + 0] * sc1 + a[0] * sc2) * linv,
                         (o0[4 * rq + 1] * sc1 + a[1] * sc2) * linv);
            v0.y = cvtpk((o0[4 * rq + 2] * sc1 + a[2] * sc2) * linv,
                         (o0[4 * rq + 3] * sc1 + a[3] * sc2) * linv);
            v1.x = cvtpk((o1[4 * rq + 0] * sc1 + c[0] * sc2) * linv,
                         (o1[4 * rq + 1] * sc1 + c[1] * sc2) * linv);
            v1.y = cvtpk((o1[4 * rq + 2] * sc1 + c[2] * sc2) * linv,
                         (o1[4 * rq + 3] * sc1 + c[3] * sc2) * linv);
            *(uint2*)&Ao[8 * rq + 4 * hi]      = v0;
            *(uint2*)&Ao[32 + 8 * rq + 4 * hi] = v1;
        }
    }
}

// ---------------------------------------------------------------------------
extern "C" void kernel_launch(void* const* d_in, const int* in_sizes, int n_in,
                              void* d_out, int out_size, void* d_ws, size_t ws_size,
                              hipStream_t stream)
{
    const float* x  = (const float*)d_in[0];
    const float* Wq = (const float*)d_in[1];
    const float* Wk = (const float*)d_in[2];
    const float* Wv = (const float*)d_in[3];
    const float* Wo = (const float*)d_in[4];
    float* out = (float*)d_out;

    ushort* xb   = (ushort*)d_ws;                       // [4096][1024]
    ushort* Wqkv = xb + (size_t)M_TOTAL * D_MODEL;      // [3072][1024]
    ushort* Wob  = Wqkv + (size_t)3 * D_MODEL * D_MODEL;// [1024][1024]
    ushort* q    = Wob + (size_t)D_MODEL * D_MODEL;     // [B,H,S,Dk]
    ushort* k    = q + (size_t)M_TOTAL * D_MODEL;       // [B,H,S,Dk]
    ushort* vt   = k + (size_t)M_TOTAL * D_MODEL;       // [B,H,Dk,S]
    ushort* ao   = vt + (size_t)M_TOTAL * D_MODEL;      // [B,S,D]

    hipLaunchKernelGGL(cast_all, dim3(8192), dim3(256), 0, stream,
                       x, Wq, Wk, Wv, Wo, xb, Wqkv, Wob);

    hipLaunchKernelGGL((gemm_bf16<1>), dim3(3 * D_MODEL / 128, M_TOTAL / 128), dim3(256),
                       0, stream, xb, Wqkv, q, k, vt, M_TOTAL, 3 * D_MODEL, D_MODEL);

    hipLaunchKernelGGL(attn_mfma, dim3(SEQ / 128, N_HEADS, BATCH), dim3(512),
                       0, stream, q, k, vt, ao);

    hipLaunchKernelGGL((gemm_bf16<0>), dim3(D_MODEL / 128, M_TOTAL / 128), dim3(256),
                       0, stream, ao, Wob, out, (void*)0, (void*)0,
                       M_TOTAL, D_MODEL, D_MODEL);
}